// Round 1
// 688.879 us; speedup vs baseline: 2.2154x; 2.2154x over previous
//
#include <hip/hip_runtime.h>
#include <hip/hip_bf16.h>

typedef __bf16 bf16;
typedef __bf16 bf16x8 __attribute__((ext_vector_type(8)));
typedef __bf16 bf16x4 __attribute__((ext_vector_type(4)));
typedef float f32x4 __attribute__((ext_vector_type(4)));

#define S_LEN 2048
#define D_MOD 512
#define NHEAD 8
#define DHEAD 64
#define NBATCH 2

// flags[1]: mask mode: 0 = 4-byte elems (int32/fp32), 1 = 1-byte, 2 = 2-byte (bf16)
__global__ void detect_kernel(const unsigned char* __restrict__ m, int* __restrict__ flags) {
    __shared__ int s4[4];
    int t = threadIdx.x;
    if (t < 4) s4[t] = 0;
    __syncthreads();
    int c3F = 0, c80p0 = 0, cnzo = 0;
    for (int i = t; i < 4096; i += 256) {
        unsigned b = m[i];
        c3F += (b == 0x3F);
        c80p0 += ((b == 0x80) && ((i & 3) == 0));
        cnzo += ((b != 0) && ((i & 3) != 0));
    }
    atomicAdd(&s4[1], c3F);
    atomicAdd(&s4[2], c80p0);
    atomicAdd(&s4[3], cnzo);
    __syncthreads();
    if (t == 0) {
        int mode;
        if (s4[1] > 0)      mode = (s4[2] > 0) ? 2 : 0;
        else if (s4[3] > 0) mode = 1;
        else                mode = 0;
        flags[1] = mode;
    }
}

__global__ void maskconv_kernel(const unsigned char* __restrict__ m,
                                const int* __restrict__ flags,
                                unsigned char* __restrict__ out) {
    long i = ((long)blockIdx.x * 256 + threadIdx.x) * 4;
    int mode = flags[1];
    uchar4 v;
    if (mode == 0) {
        const int* mi = (const int*)m;
        v.x = (unsigned char)(mi[i + 0] != 0);
        v.y = (unsigned char)(mi[i + 1] != 0);
        v.z = (unsigned char)(mi[i + 2] != 0);
        v.w = (unsigned char)(mi[i + 3] != 0);
    } else if (mode == 1) {
        uchar4 r = *(const uchar4*)(m + i);
        v.x = (r.x != 0); v.y = (r.y != 0); v.z = (r.z != 0); v.w = (r.w != 0);
    } else {
        const unsigned short* ms = (const unsigned short*)m;
        v.x = (unsigned char)(ms[i + 0] != 0);
        v.y = (unsigned char)(ms[i + 1] != 0);
        v.z = (unsigned char)(ms[i + 2] != 0);
        v.w = (unsigned char)(ms[i + 3] != 0);
    }
    *(uchar4*)(out + i) = v;
}

// ---------- fp32 -> (hi,lo) bf16 split, elementwise ----------
__global__ __launch_bounds__(256) void packA(const float* __restrict__ src,
                                             bf16* __restrict__ outh,
                                             bf16* __restrict__ outl) {
    long i = ((long)blockIdx.x * 256 + threadIdx.x) * 4;
    f32x4 v = *(const f32x4*)(src + i);
    bf16x4 h, l;
    #pragma unroll
    for (int j = 0; j < 4; ++j) {
        bf16 hh = (bf16)v[j];
        h[j] = hh;
        l[j] = (bf16)(v[j] - (float)hh);
    }
    *(bf16x4*)(outh + i) = h;
    *(bf16x4*)(outl + i) = l;
}

// ---------- W [K,N] fp32 -> W^T (hi,lo) bf16 [N,K], tiled transpose ----------
__global__ __launch_bounds__(256) void packWT(const float* __restrict__ W,
                                              bf16* __restrict__ outh,
                                              bf16* __restrict__ outl,
                                              int K, int N) {
    __shared__ float tile[64][65];
    int n0 = blockIdx.x * 64, k0 = blockIdx.y * 64;
    int t = threadIdx.x, tx = t & 63, ty = t >> 6;
    #pragma unroll
    for (int r = ty; r < 64; r += 4)
        tile[r][tx] = W[(long)(k0 + r) * N + n0 + tx];
    __syncthreads();
    #pragma unroll
    for (int r = ty; r < 64; r += 4) {
        float v = tile[tx][r];            // = W[k0+tx][n0+r]
        bf16 h = (bf16)v;
        long idx = (long)(n0 + r) * K + k0 + tx;
        outh[idx] = h;
        outl[idx] = (bf16)(v - (float)h);
    }
}

// ---------- split-bf16 MFMA GEMM: C[M,N] = (Ahi+Alo)[M,K] @ (Bhi+Blo)^T ----------
// B operands are pre-transposed: Bth/Btl are [N,K] (so both MFMA operands read
// identically: frag = rows of the tile, k along the row — exact attn_kernel pattern).
// 3-MFMA error compensation: hi*hi + hi*lo + lo*hi  (lo*lo ~2^-18 rel, dropped).
// Tile: BM=64, BN=128, BK=32; 256 thr = 4 waves, wave w owns cols [w*32, w*32+32).
// EPI 0: +bias -> fp32 out
// EPI 1: +bias, relu -> (hi,lo) bf16 pair out
// EPI 2: +bias +res  -> fp32 out
template<int EPI>
__global__ __launch_bounds__(256) void mgemm(
    const bf16* __restrict__ Ahi, const bf16* __restrict__ Alo,
    const bf16* __restrict__ Bth, const bf16* __restrict__ Btl,
    const float* __restrict__ bias, const float* __restrict__ res,
    float* __restrict__ outf, bf16* __restrict__ outh, bf16* __restrict__ outl,
    int M, int N, int K)
{
    // +8 bf16 (16B) pad keeps every bf16x8 access 16B-aligned and breaks bank stride
    __shared__ bf16 sAh[64][40], sAl[64][40], sBh[128][40], sBl[128][40];

    int t = threadIdx.x;
    int lane = t & 63, wave = t >> 6;
    int lm = lane & 15, quad = lane >> 4;
    int m0 = blockIdx.y * 64, n0 = blockIdx.x * 128;

    // staging coords: 4 threads per row, one bf16x8 (16B) each
    int ar = t >> 2, ac = (t & 3) * 8;
    const bf16* Aph = Ahi + (long)(m0 + ar) * K + ac;
    const bf16* Apl = Alo + (long)(m0 + ar) * K + ac;
    const bf16* Bph0 = Bth + (long)(n0 + ar) * K + ac;
    const bf16* Bph1 = Bth + (long)(n0 + 64 + ar) * K + ac;
    const bf16* Bpl0 = Btl + (long)(n0 + ar) * K + ac;
    const bf16* Bpl1 = Btl + (long)(n0 + 64 + ar) * K + ac;

    f32x4 acc[4][2] = {};

    for (int k0 = 0; k0 < K; k0 += 32) {
        // issue global loads first: latency overlaps previous tile's compute
        bf16x8 va = *(const bf16x8*)(Aph + k0);
        bf16x8 vb = *(const bf16x8*)(Apl + k0);
        bf16x8 v0 = *(const bf16x8*)(Bph0 + k0);
        bf16x8 v1 = *(const bf16x8*)(Bph1 + k0);
        bf16x8 v2 = *(const bf16x8*)(Bpl0 + k0);
        bf16x8 v3 = *(const bf16x8*)(Bpl1 + k0);
        __syncthreads();
        *(bf16x8*)&sAh[ar][ac] = va;
        *(bf16x8*)&sAl[ar][ac] = vb;
        *(bf16x8*)&sBh[ar][ac] = v0;
        *(bf16x8*)&sBh[ar + 64][ac] = v1;
        *(bf16x8*)&sBl[ar][ac] = v2;
        *(bf16x8*)&sBl[ar + 64][ac] = v3;
        __syncthreads();

        bf16x8 ah[4], al[4], bh[2], bl[2];
        #pragma unroll
        for (int i = 0; i < 4; ++i) {
            ah[i] = *(const bf16x8*)&sAh[i * 16 + lm][quad * 8];
            al[i] = *(const bf16x8*)&sAl[i * 16 + lm][quad * 8];
        }
        #pragma unroll
        for (int j = 0; j < 2; ++j) {
            int r = wave * 32 + j * 16 + lm;
            bh[j] = *(const bf16x8*)&sBh[r][quad * 8];
            bl[j] = *(const bf16x8*)&sBl[r][quad * 8];
        }
        #pragma unroll
        for (int i = 0; i < 4; ++i)
            #pragma unroll
            for (int j = 0; j < 2; ++j) {
                acc[i][j] = __builtin_amdgcn_mfma_f32_16x16x32_bf16(ah[i], bh[j], acc[i][j], 0, 0, 0);
                acc[i][j] = __builtin_amdgcn_mfma_f32_16x16x32_bf16(ah[i], bl[j], acc[i][j], 0, 0, 0);
                acc[i][j] = __builtin_amdgcn_mfma_f32_16x16x32_bf16(al[i], bh[j], acc[i][j], 0, 0, 0);
            }
    }

    #pragma unroll
    for (int i = 0; i < 4; ++i)
        #pragma unroll
        for (int j = 0; j < 2; ++j) {
            int gn = n0 + wave * 32 + j * 16 + lm;
            float bv = bias[gn];
            #pragma unroll
            for (int r = 0; r < 4; ++r) {
                int gm = m0 + i * 16 + quad * 4 + r;
                long idx = (long)gm * N + gn;
                float v = acc[i][j][r] + bv;
                if (EPI == 1) {
                    v = fmaxf(v, 0.f);
                    bf16 h = (bf16)v;
                    outh[idx] = h;
                    outl[idx] = (bf16)(v - (float)h);
                } else {
                    if (EPI == 2) v += res[idx];
                    outf[idx] = v;
                }
            }
        }
}

// ---------- pack fp32 [B*S, H*64] -> bf16 [B,H,S,64] ----------
__global__ void pack_qk(const float* __restrict__ src, bf16* __restrict__ dst) {
    long idx = (long)blockIdx.x * 256 + threadIdx.x;
    int mrow = (int)(idx >> 9), n = (int)(idx & 511);
    int b = mrow >> 11, s = mrow & 2047, h = n >> 6, d = n & 63;
    dst[(((long)(b * NHEAD + h) * S_LEN + s) << 6) + d] = (bf16)src[idx];
}
// ---------- pack fp32 [B*S, H*64] -> bf16 [B,H,64,S] (V^T) ----------
__global__ void pack_v(const float* __restrict__ src, bf16* __restrict__ dst) {
    long idx = (long)blockIdx.x * 256 + threadIdx.x;
    int mrow = (int)(idx >> 9), n = (int)(idx & 511);
    int b = mrow >> 11, s = mrow & 2047, h = n >> 6, d = n & 63;
    dst[(((long)(b * NHEAD + h) * DHEAD + d) << 11) + s] = (bf16)src[idx];
}

// ---------- MFMA attention: two-pass softmax; fp32 probs + fp32 ctx ----------
__global__ __launch_bounds__(256) void attn_kernel(
    const bf16* __restrict__ Q, const bf16* __restrict__ Kg,
    const bf16* __restrict__ Vt, const unsigned char* __restrict__ mask8,
    float* __restrict__ attnO, float* __restrict__ ctxf)
{
    __shared__ bf16 Qs[64][72];
    __shared__ bf16 Ks[64][72];
    __shared__ bf16 Vs[64][72];
    __shared__ bf16 Ps[64][72];

    int t = threadIdx.x;
    int qt = blockIdx.x & 31, bh = blockIdx.x >> 5;
    int b_ = bh >> 3, h_ = bh & 7;
    int q0 = qt * 64;
    int lane = t & 63, wave = t >> 6;
    int lm = lane & 15, quad = lane >> 4, q8 = quad * 8;
    int sr = t >> 2, sc = (t & 3) * 16;

    const bf16* Qp = Q + (long)bh * (S_LEN * DHEAD) + (long)(q0 + sr) * DHEAD + sc;
    *(bf16x8*)&Qs[sr][sc]     = *(const bf16x8*)(Qp);
    *(bf16x8*)&Qs[sr][sc + 8] = *(const bf16x8*)(Qp + 8);

    float mrow[4], lrow[4];
    #pragma unroll
    for (int r = 0; r < 4; ++r) { mrow[r] = -1e30f; lrow[r] = 0.f; }

    const bf16* Kbase = Kg + (long)bh * (S_LEN * DHEAD);
    const unsigned char* Mbase = mask8 + (long)b_ * S_LEN * S_LEN;

    // pass 1: row max + sum(exp)
    for (int kt = 0; kt < 32; ++kt) {
        int k0 = kt * 64;
        __syncthreads();
        const bf16* Kp = Kbase + (long)(k0 + sr) * DHEAD + sc;
        *(bf16x8*)&Ks[sr][sc]     = *(const bf16x8*)(Kp);
        *(bf16x8*)&Ks[sr][sc + 8] = *(const bf16x8*)(Kp + 8);
        __syncthreads();

        f32x4 sacc[4] = {};
        bf16x8 a0 = *(const bf16x8*)&Qs[wave * 16 + lm][q8];
        bf16x8 a1 = *(const bf16x8*)&Qs[wave * 16 + lm][32 + q8];
        #pragma unroll
        for (int tn = 0; tn < 4; ++tn) {
            bf16x8 b0 = *(const bf16x8*)&Ks[tn * 16 + lm][q8];
            bf16x8 b1 = *(const bf16x8*)&Ks[tn * 16 + lm][32 + q8];
            sacc[tn] = __builtin_amdgcn_mfma_f32_16x16x32_bf16(a0, b0, sacc[tn], 0, 0, 0);
            sacc[tn] = __builtin_amdgcn_mfma_f32_16x16x32_bf16(a1, b1, sacc[tn], 0, 0, 0);
        }
        #pragma unroll
        for (int r = 0; r < 4; ++r) {
            int grow = q0 + wave * 16 + quad * 4 + r;
            const unsigned char* Mr = Mbase + (long)grow * S_LEN + k0 + lm;
            float sv[4];
            float tmax = -1e30f;
            #pragma unroll
            for (int tn = 0; tn < 4; ++tn) {
                float s = sacc[tn][r] * 0.125f;
                if (Mr[tn * 16]) s = -1e9f;
                sv[tn] = s;
                tmax = fmaxf(tmax, s);
            }
            #pragma unroll
            for (int off = 8; off; off >>= 1) tmax = fmaxf(tmax, __shfl_xor(tmax, off));
            float mnew = fmaxf(mrow[r], tmax);
            float es = 0.f;
            #pragma unroll
            for (int tn = 0; tn < 4; ++tn) es += __expf(sv[tn] - mnew);
            #pragma unroll
            for (int off = 8; off; off >>= 1) es += __shfl_xor(es, off);
            lrow[r] = lrow[r] * __expf(mrow[r] - mnew) + es;
            mrow[r] = mnew;
        }
    }
    float rl[4];
    #pragma unroll
    for (int r = 0; r < 4; ++r) rl[r] = 1.f / lrow[r];

    float* attnBase = attnO + (long)bh * S_LEN * S_LEN;
    const bf16* Vbase = Vt + (long)bh * (DHEAD * S_LEN);
    f32x4 oacc[4] = {};

    // pass 2: recompute scores, write fp32 probs, accumulate PV
    for (int kt = 0; kt < 32; ++kt) {
        int k0 = kt * 64;
        __syncthreads();
        const bf16* Kp = Kbase + (long)(k0 + sr) * DHEAD + sc;
        *(bf16x8*)&Ks[sr][sc]     = *(const bf16x8*)(Kp);
        *(bf16x8*)&Ks[sr][sc + 8] = *(const bf16x8*)(Kp + 8);
        const bf16* Vp = Vbase + (long)sr * S_LEN + k0 + sc;
        *(bf16x8*)&Vs[sr][sc]     = *(const bf16x8*)(Vp);
        *(bf16x8*)&Vs[sr][sc + 8] = *(const bf16x8*)(Vp + 8);
        __syncthreads();

        f32x4 sacc[4] = {};
        bf16x8 a0 = *(const bf16x8*)&Qs[wave * 16 + lm][q8];
        bf16x8 a1 = *(const bf16x8*)&Qs[wave * 16 + lm][32 + q8];
        #pragma unroll
        for (int tn = 0; tn < 4; ++tn) {
            bf16x8 b0 = *(const bf16x8*)&Ks[tn * 16 + lm][q8];
            bf16x8 b1 = *(const bf16x8*)&Ks[tn * 16 + lm][32 + q8];
            sacc[tn] = __builtin_amdgcn_mfma_f32_16x16x32_bf16(a0, b0, sacc[tn], 0, 0, 0);
            sacc[tn] = __builtin_amdgcn_mfma_f32_16x16x32_bf16(a1, b1, sacc[tn], 0, 0, 0);
        }
        #pragma unroll
        for (int r = 0; r < 4; ++r) {
            int grow = q0 + wave * 16 + quad * 4 + r;
            const unsigned char* Mr = Mbase + (long)grow * S_LEN + k0 + lm;
            #pragma unroll
            for (int tn = 0; tn < 4; ++tn) {
                float s = sacc[tn][r] * 0.125f;
                if (Mr[tn * 16]) s = -1e9f;
                float p = __expf(s - mrow[r]) * rl[r];
                attnBase[(long)grow * S_LEN + k0 + tn * 16 + lm] = p;
                Ps[wave * 16 + quad * 4 + r][tn * 16 + lm] = (bf16)p;
            }
        }
        __syncthreads();
        bf16x8 pa0 = *(const bf16x8*)&Ps[wave * 16 + lm][q8];
        bf16x8 pa1 = *(const bf16x8*)&Ps[wave * 16 + lm][32 + q8];
        #pragma unroll
        for (int td = 0; td < 4; ++td) {
            bf16x8 v0 = *(const bf16x8*)&Vs[td * 16 + lm][q8];
            bf16x8 v1 = *(const bf16x8*)&Vs[td * 16 + lm][32 + q8];
            oacc[td] = __builtin_amdgcn_mfma_f32_16x16x32_bf16(pa0, v0, oacc[td], 0, 0, 0);
            oacc[td] = __builtin_amdgcn_mfma_f32_16x16x32_bf16(pa1, v1, oacc[td], 0, 0, 0);
        }
    }

    // ctx fp32 [B*S, H*64]
    #pragma unroll
    for (int td = 0; td < 4; ++td)
    #pragma unroll
    for (int r = 0; r < 4; ++r) {
        int grow = q0 + wave * 16 + quad * 4 + r;
        ctxf[(long)(b_ * S_LEN + grow) * D_MOD + h_ * 64 + td * 16 + lm] = oacc[td][r];
    }
}

// ---------- layernorm over D=512, fp32 in / fp32 out ----------
__global__ __launch_bounds__(256) void ln_kernel(
    const float* __restrict__ X, const float* __restrict__ g,
    const float* __restrict__ bb, float* __restrict__ out)
{
    __shared__ float red[8];
    int row = blockIdx.x, t = threadIdx.x;
    float x0 = X[(long)row * 512 + t];
    float x1 = X[(long)row * 512 + 256 + t];
    float s = x0 + x1, ss = x0 * x0 + x1 * x1;
    #pragma unroll
    for (int off = 32; off; off >>= 1) { s += __shfl_xor(s, off); ss += __shfl_xor(ss, off); }
    if ((t & 63) == 0) { red[t >> 6] = s; red[4 + (t >> 6)] = ss; }
    __syncthreads();
    float S_ = red[0] + red[1] + red[2] + red[3];
    float SS = red[4] + red[5] + red[6] + red[7];
    float mu = S_ * (1.f / 512.f);
    float var = SS * (1.f / 512.f) - mu * mu;
    float is = rsqrtf(var + 1e-5f);
    out[(long)row * 512 + t]       = (x0 - mu) * is * g[t]       + bb[t];
    out[(long)row * 512 + 256 + t] = (x1 - mu) * is * g[t + 256] + bb[t + 256];
}

// ---------------- host launch ----------------
extern "C" void kernel_launch(void* const* d_in, const int* in_sizes, int n_in,
                              void* d_out, int out_size, void* d_ws, size_t ws_size,
                              hipStream_t stream)
{
    const float* x = (const float*)d_in[0];
    const unsigned char* maskraw = (const unsigned char*)d_in[1];
    const float* Wq = (const float*)d_in[2];  const float* bq = (const float*)d_in[3];
    const float* Wk = (const float*)d_in[4];  const float* bk = (const float*)d_in[5];
    const float* Wv = (const float*)d_in[6];  const float* bv = (const float*)d_in[7];
    const float* Wo = (const float*)d_in[8];  const float* bo = (const float*)d_in[9];
    const float* ln1g = (const float*)d_in[10]; const float* ln1b = (const float*)d_in[11];
    const float* W1 = (const float*)d_in[12]; const float* b1f = (const float*)d_in[13];
    const float* W2 = (const float*)d_in[14]; const float* b2f = (const float*)d_in[15];
    const float* ln2g = (const float*)d_in[16]; const float* ln2b = (const float*)d_in[17];

    // OUTPUTS ARE FP32: out [B*S*D] then attn [B*H*S*S], concatenated flat.
    float* outMain = (float*)d_out;
    float* outAttn = outMain + (size_t)NBATCH * S_LEN * D_MOD;

    char* w = (char*)d_ws;
    size_t off = 0;
    auto alloc = [&](size_t bytes) -> char* {
        char* p = w + off;
        off += (bytes + 255) & ~(size_t)255;
        return p;
    };
    const size_t MB = 1024 * 1024;
    int* flags = (int*)alloc(256);
    unsigned char* mask8 = (unsigned char*)alloc(8 * MB);
    // contiguous 32MB span {qf,kf,vf,ctxf}; later aliased by hh/hl (bf16 4096x2048 x2)
    float* qf   = (float*)alloc(8 * MB);
    float* kf   = (float*)alloc(8 * MB);
    float* vf   = (float*)alloc(8 * MB);
    float* ctxf = (float*)alloc(8 * MB);
    float* tmp   = (float*)alloc(8 * MB);
    float* aoutf = (float*)alloc(8 * MB);
    bf16* Qb   = (bf16*)alloc(4 * MB);
    bf16* Kb   = (bf16*)alloc(4 * MB);
    bf16* Vtb  = (bf16*)alloc(4 * MB);
    // activation hi/lo split (reused: x, then ctx, then attn_out) — [4096,512] bf16
    bf16* xh = (bf16*)alloc(4 * MB);
    bf16* xl = (bf16*)alloc(4 * MB);
    // transposed+split QKVO weights [512,512] bf16 each
    bf16* WqTh = (bf16*)alloc(512 * 1024); bf16* WqTl = (bf16*)alloc(512 * 1024);
    bf16* WkTh = (bf16*)alloc(512 * 1024); bf16* WkTl = (bf16*)alloc(512 * 1024);
    bf16* WvTh = (bf16*)alloc(512 * 1024); bf16* WvTl = (bf16*)alloc(512 * 1024);
    bf16* WoTh = (bf16*)alloc(512 * 1024); bf16* WoTl = (bf16*)alloc(512 * 1024);
    // aliases (dead-buffer reuse):
    bf16* hh = (bf16*)qf;                    // [4096,2048] hi : 16MB over qf+kf
    bf16* hl = (bf16*)vf;                    // [4096,2048] lo : 16MB over vf+ctxf
    bf16* W1Th = (bf16*)Qb;                  // [2048,512] : 2MB
    bf16* W1Tl = W1Th + (size_t)2048 * 512;  // 2MB (fits Qb's 4MB)
    bf16* W2Th = (bf16*)Kb;                  // [512,2048] : 2MB
    bf16* W2Tl = W2Th + (size_t)512 * 2048;  // 2MB (fits Kb's 4MB)

    const int M = NBATCH * S_LEN;  // 4096

    detect_kernel<<<1, 256, 0, stream>>>(maskraw, flags);
    maskconv_kernel<<<(NBATCH * S_LEN * S_LEN) / 1024, 256, 0, stream>>>(maskraw, flags, mask8);

    // weight transpose+split (QKVO now; W1/W2 after attn since they alias Qb/Kb)
    packWT<<<dim3(8, 8), 256, 0, stream>>>(Wq, WqTh, WqTl, 512, 512);
    packWT<<<dim3(8, 8), 256, 0, stream>>>(Wk, WkTh, WkTl, 512, 512);
    packWT<<<dim3(8, 8), 256, 0, stream>>>(Wv, WvTh, WvTl, 512, 512);
    packWT<<<dim3(8, 8), 256, 0, stream>>>(Wo, WoTh, WoTl, 512, 512);

    // QKV projections: split-bf16 MFMA GEMM
    packA<<<(M * 512) / 1024, 256, 0, stream>>>(x, xh, xl);
    mgemm<0><<<dim3(4, 64), 256, 0, stream>>>(xh, xl, WqTh, WqTl, bq, nullptr, qf, nullptr, nullptr, M, 512, 512);
    mgemm<0><<<dim3(4, 64), 256, 0, stream>>>(xh, xl, WkTh, WkTl, bk, nullptr, kf, nullptr, nullptr, M, 512, 512);
    mgemm<0><<<dim3(4, 64), 256, 0, stream>>>(xh, xl, WvTh, WvTl, bv, nullptr, vf, nullptr, nullptr, M, 512, 512);

    // bf16 packs for MFMA attention
    pack_qk<<<(M * 512) / 256, 256, 0, stream>>>(qf, Qb);
    pack_qk<<<(M * 512) / 256, 256, 0, stream>>>(kf, Kb);
    pack_v<<<(M * 512) / 256, 256, 0, stream>>>(vf, Vtb);

    // fused MFMA attention: fp32 probs (Output 1) + fp32 context
    attn_kernel<<<512, 256, 0, stream>>>(Qb, Kb, Vtb, mask8, outAttn, ctxf);

    // FFN weights (Qb/Kb dead now)
    packWT<<<dim3(32, 8), 256, 0, stream>>>(W1, W1Th, W1Tl, 512, 2048);
    packWT<<<dim3(8, 32), 256, 0, stream>>>(W2, W2Th, W2Tl, 2048, 512);

    // out-proj + residual, then LN1
    packA<<<(M * 512) / 1024, 256, 0, stream>>>(ctxf, xh, xl);
    mgemm<2><<<dim3(4, 64), 256, 0, stream>>>(xh, xl, WoTh, WoTl, bo, x, tmp, nullptr, nullptr, M, 512, 512);
    ln_kernel<<<M, 256, 0, stream>>>(tmp, ln1g, ln1b, aoutf);

    // FFN: W1 emits relu'd (hi,lo) bf16 directly (no fp32 h buffer)
    packA<<<(M * 512) / 1024, 256, 0, stream>>>(aoutf, xh, xl);
    mgemm<1><<<dim3(16, 64), 256, 0, stream>>>(xh, xl, W1Th, W1Tl, b1f, nullptr, nullptr, hh, hl, M, 2048, 512);
    mgemm<2><<<dim3(4, 64), 256, 0, stream>>>(hh, hl, W2Th, W2Tl, b2f, aoutf, tmp, nullptr, nullptr, M, 512, 2048);
    ln_kernel<<<M, 256, 0, stream>>>(tmp, ln2g, ln2b, outMain);

    (void)in_sizes; (void)n_in; (void)out_size; (void)ws_size;
}